// Round 10
// baseline (493.058 us; speedup 1.0000x reference)
//
#include <hip/hip_runtime.h>
#include <hip/hip_bf16.h>

typedef unsigned short u16;
typedef __bf16 bf16x8 __attribute__((ext_vector_type(8)));
typedef float f32x4 __attribute__((ext_vector_type(4)));
typedef float f32x16 __attribute__((ext_vector_type(16)));

#define B_   2
#define S_   2048
#define HID_ 2048
#define H_   16
#define KV_  4
#define D_   128
#define TS_  5120  // merged qkv token stride (4096 q|gate + 512 k + 512 v)

template <int V> struct ic { static constexpr int value = V; };

__device__ __forceinline__ u16 f2b(float f) {
  unsigned u = __float_as_uint(f);
  return (u16)((u + 0x7fffu + ((u >> 16) & 1u)) >> 16);  // RNE
}
__device__ __forceinline__ float b2f(u16 h) {
  return __uint_as_float(((unsigned)h) << 16);
}
__device__ __forceinline__ unsigned pk2(float a, float b) {
  __hip_bfloat162 h = __float22bfloat162_rn(make_float2(a, b));
  unsigned u;
  __builtin_memcpy(&u, &h, 4);
  return u;  // a low 16, b high 16
}
__device__ __forceinline__ void cstore(float* p, float v) { *p = v; }
__device__ __forceinline__ void cstore(u16* p, float v)   { *p = f2b(v); }

// async global->LDS, 16B per lane; LDS dest = wave-uniform base + lane*16
__device__ __forceinline__ void gl_lds16(const u16* g, u16* l) {
  __builtin_amdgcn_global_load_lds(
      (const __attribute__((address_space(1))) unsigned int*)g,
      (__attribute__((address_space(3))) unsigned int*)l, 16, 0, 0);
}

// GEMM-operand fragment layout for an (R x K) matrix, R%16==0, K%32==0:
//   addr(r,k) = (((r>>4)*(K>>5) + (k>>5))*64 + ((k>>3)&3)*16 + (r&15))*8 + (k&7)
// One (tile,kstep) block = 1KB, lane l = oct(l>>4)*16 + row(l&15) — exactly the
// mfma_16x16x32 A/B fragment. Staging reads are lane-contiguous 1KB; LDS reads
// linear; both conflict- and scatter-free.

// ---------------- prep0: {Wq,Wk,Wv,Wo transpose->B-frag} + {cast x->A-frag}
// fused into one range-decoded launch (was 5 launches -> 1).
__global__ __launch_bounds__(256)
void prep0_kernel(const float* __restrict__ Wq, const float* __restrict__ Wk,
                  const float* __restrict__ Wv, const float* __restrict__ Wo,
                  const float* __restrict__ x, u16* __restrict__ Wqt,
                  u16* __restrict__ Wkvt, u16* __restrict__ Wot,
                  u16* __restrict__ xb) {
  __shared__ u16 t[32][33];
  const int tid = threadIdx.x;
  int idx = blockIdx.x;
  if (idx >= 14336) {  // ---- cast x -> bf16 A-frag (4096 blocks)
    idx -= 14336;
    const int gi = idx * 256 + tid;
    const int r = gi >> 8;
    const int k = (gi & 255) << 3;
    const float4 v0 = *(const float4*)(x + (size_t)r * 2048 + k);
    const float4 v1 = *(const float4*)(x + (size_t)r * 2048 + k + 4);
    uint4 w;
    w.x = pk2(v0.x, v0.y); w.y = pk2(v0.z, v0.w);
    w.z = pk2(v1.x, v1.y); w.w = pk2(v1.z, v1.w);
    const size_t off =
        ((((size_t)(r >> 4) * 64 + (k >> 5)) * 64) + ((k >> 3) & 3) * 16 +
         (r & 15)) * 8;
    *(uint4*)(xb + off) = w;
    return;
  }
  // ---- W transpose -> B-frag layout
  const float* in; u16* out; int Cc, bx, by;
  if (idx < 8192)       { in = Wq; out = Wqt; Cc = 4096; bx = idx & 127; by = idx >> 7; }
  else if (idx < 9216)  { idx -= 8192; in = Wk; out = Wkvt; Cc = 512; bx = idx & 15; by = idx >> 4; }
  else if (idx < 10240) { idx -= 9216; in = Wv; out = Wkvt + (size_t)512 * 2048; Cc = 512; bx = idx & 15; by = idx >> 4; }
  else                  { idx -= 10240; in = Wo; out = Wot; Cc = 2048; bx = idx & 63; by = idx >> 6; }
  const int R = 2048;  // K-dim for all weight operands
  const int tx = tid & 31, ty = tid >> 5;
  const int c0 = bx * 32, r0 = by * 32;
#pragma unroll
  for (int i = 0; i < 4; i++)
    t[ty + i * 8][tx] = f2b(in[(size_t)(r0 + ty + i * 8) * Cc + c0 + tx]);
  __syncthreads();
  if (tid < 128) {
    const int tl = tid >> 6, l = tid & 63, li = l & 15, quad = l >> 4;
    u16 vals[8];
#pragma unroll
    for (int e = 0; e < 8; e++) vals[e] = t[quad * 8 + e][tl * 16 + li];
    const size_t off =
        ((((size_t)(c0 >> 4) + tl) * (R >> 5) + (r0 >> 5)) * 64 + quad * 16 +
         li) * 8;
    *(uint4*)(out + off) = *(const uint4*)vals;
  }
}

// ---------------- rmsrope body: fused RMSNorm (w+1) + RoPE, attn-frag output
__device__ __forceinline__ void rmsrope_body(
    int relblk, int tid, const u16* __restrict__ in,
    const float* __restrict__ w, u16* __restrict__ out, int n_heads,
    int head_stride, float scale) {
  const int warp = (relblk << 2) + (tid >> 6);
  const int lane = tid & 63;
  const int h = warp % n_heads;
  const int tok = warp / n_heads;
  const int s = tok & (S_ - 1);
  const int b = tok >> 11;
  const u16* src = in + (size_t)tok * TS_ + (size_t)h * head_stride;
  float x1 = b2f(src[lane]);
  float x2 = b2f(src[lane + 64]);
  float ss = x1 * x1 + x2 * x2;
#pragma unroll
  for (int off = 1; off < 64; off <<= 1) ss += __shfl_xor(ss, off);
  const float inv = rsqrtf(ss * (1.0f / 128.0f) + 1e-6f) * scale;
  x1 *= inv * (w[lane] + 1.0f);
  x2 *= inv * (w[lane + 64] + 1.0f);
  const float invf = exp2f((float)lane * (-19.931568569324174f / 64.0f));
  const float ang = (float)s * invf;
  float sn, c;
  sincosf(ang, &sn, &c);
  const int wq = lane >> 4, hi = (lane >> 3) & 1, e = lane & 7;
  const size_t tb = (((size_t)b * n_heads + h) * 64 + (s >> 5)) * 4096;
  const size_t o1 = tb + (size_t)(wq * 64 + hi * 32 + (s & 31)) * 8 + e;
  out[o1]        = f2b(x1 * c - x2 * sn);
  out[o1 + 2048] = f2b(x2 * c + x1 * sn);
}

// ---------------- prep1: {rmsrope Q, rmsrope K, transpose_v} fused (3 -> 1)
__global__ __launch_bounds__(256)
void prep1_kernel(const u16* __restrict__ qkraw, const float* __restrict__ qn,
                  const float* __restrict__ kn, u16* __restrict__ Qr,
                  u16* __restrict__ Kr, u16* __restrict__ Vtb) {
  const int tid = threadIdx.x;
  int blk = blockIdx.x;
  if (blk < 16384) {  // Q: 65536 head-tokens, scale folded in
    rmsrope_body(blk, tid, qkraw, qn, Qr, 16, 256, 0.08838834764831845f);
    return;
  }
  blk -= 16384;
  if (blk < 4096) {  // K
    rmsrope_body(blk, tid, qkraw + 4096, kn, Kr, 4, 128, 1.0f);
    return;
  }
  blk -= 4096;  // transpose_v: idx in [0,2048)
  __shared__ u16 t[32][33];
  const int tx = tid & 31, ty = tid >> 5;
  const int jt = blk & 63, dt = (blk >> 6) & 3, z = blk >> 8;
  const int s0 = jt * 32, d0 = dt * 32;
  const int b = z >> 2, kv = z & 3;
  const u16* in = qkraw + 4096 + 512;
#pragma unroll
  for (int i = 0; i < 4; i++)
    t[ty + i * 8][tx] =
        in[(size_t)(b * S_ + s0 + ty + i * 8) * TS_ + kv * D_ + d0 + tx];
  __syncthreads();
  if (tid < 128) {
    const int kk = tid >> 6, hi2 = (tid >> 5) & 1, d31 = tid & 31;
    u16 vals[8];
#pragma unroll
    for (int e = 0; e < 8; e++) vals[e] = t[kk * 16 + hi2 * 8 + e][d31];
    const size_t off =
        ((((size_t)(b * KV_ + kv) * 64 + jt) * 8 + dt * 2 + kk) * 64 +
         hi2 * 32 + d31) * 8;
    *(uint4*)(Vtb + off) = *(const uint4*)vals;
  }
}

// --------------------------------- NT GEMM: A, Bt in FRAGMENT layout; C (M,N)
// row-major. 128x128 tile, BK=32, gl_lds16 width=16, single-barrier LDS
// double-buffer, zero bank conflicts. XCD-pinned 1D grid, n-fastest within
// group. Requires Nd%1024==0, Md=4096.
template <typename CT>
__global__ __launch_bounds__(256)
void gemm_nt(const u16* __restrict__ A, const u16* __restrict__ Bt,
             CT* __restrict__ C, int Md, int Nd, int Kd) {
  __shared__ u16 As[2][8 * 512];  // dbuf x 8 frag-tiles x 512 (16KB)
  __shared__ u16 Bs[2][8 * 512];
  const int tid = threadIdx.x;
  const int lane = tid & 63;
  const int wave = tid >> 6;
  const int wm = wave >> 1, wn = wave & 1;
  const int li = lane & 15, quad = lane >> 4;

  // XCD-pinned decode, n-fastest within group
  const int id = blockIdx.x;
  const int grp = id & 7;
  const int r = id >> 3;
  const int px = Nd >> 10;  // N-panels per XCD (5120->5, 2048->2)
  const int m0 = (r / px) * 128;
  const int n0 = (grp * px + (r % px)) * 128;

  f32x4 acc[4][4];
#pragma unroll
  for (int i = 0; i < 4; i++)
#pragma unroll
    for (int j = 0; j < 4; j++) acc[i][j] = (f32x4){0.f, 0.f, 0.f, 0.f};

  const size_t ts = (size_t)(Kd >> 5) * 512;  // elems per frag-tile row
  const u16* Ab = A + ((size_t)(m0 >> 4) + wave * 2) * ts + lane * 8;
  const u16* Bb = Bt + ((size_t)(n0 >> 4) + wave * 2) * ts + lane * 8;

  auto stage = [&](int buf, int k0) {
    const size_t ko = (size_t)k0 * 16;  // (k0>>5)*512
    gl_lds16(Ab + ko, &As[buf][(wave * 2) * 512]);
    gl_lds16(Ab + ts + ko, &As[buf][(wave * 2 + 1) * 512]);
    gl_lds16(Bb + ko, &Bs[buf][(wave * 2) * 512]);
    gl_lds16(Bb + ts + ko, &Bs[buf][(wave * 2 + 1) * 512]);
  };

  stage(0, 0);
  int cur = 0;
  for (int k0 = 0; k0 < Kd; k0 += 32) {
    __syncthreads();  // drains the stage of buf[cur] (issued last iter/prologue)
    if (k0 + 32 < Kd) stage(cur ^ 1, k0 + 32);
    bf16x8 af[4], bfr[4];
#pragma unroll
    for (int mt = 0; mt < 4; mt++)
      af[mt] = *(const bf16x8*)&As[cur][(wm * 4 + mt) * 512 + lane * 8];
#pragma unroll
    for (int nt = 0; nt < 4; nt++)
      bfr[nt] = *(const bf16x8*)&Bs[cur][(wn * 4 + nt) * 512 + lane * 8];
#pragma unroll
    for (int mt = 0; mt < 4; mt++)
#pragma unroll
      for (int nt = 0; nt < 4; nt++)
        acc[mt][nt] = __builtin_amdgcn_mfma_f32_16x16x32_bf16(
            af[mt], bfr[nt], acc[mt][nt], 0, 0, 0);
    cur ^= 1;
  }
#pragma unroll
  for (int mt = 0; mt < 4; mt++) {
    const int row = m0 + wm * 64 + mt * 16 + quad * 4;
#pragma unroll
    for (int nt = 0; nt < 4; nt++) {
      const int col = n0 + wn * 64 + nt * 16 + li;
#pragma unroll
      for (int r2 = 0; r2 < 4; r2++)
        cstore(&C[(size_t)(row + r2) * Nd + col], acc[mt][nt][r2]);
    }
  }
}

// --------------------------- flash attention: 4-wave split-K per 32-row strip
// (256-thread blocks). Each wave runs the wave-autonomous 32x32 step loop over
// a QUARTER of the strip's K-tiles; 4-way flash-decode merge through LDS
// (each wave dumps 3 foreign 32x32 d-slices, finalizes its own). Supply
// 32 waves/CU, residency 3 blocks/CU (51.7KB LDS, VGPR<=170 via
// launch_bounds). Swapped QK^T, in-register P exchange, defer-max THR=8,
// XCD-pinned decode, heavy-strips-first, T5 setprio. Q/K/V pre-fragmented.
// All oacc[] indices compile-time (rule #20) via 4-way templated epilogue.
__global__ __launch_bounds__(256, 3)
void attn_kernel(const u16* __restrict__ Q, const u16* __restrict__ Kr,
                 const u16* __restrict__ Vt, const u16* __restrict__ qraw,
                 u16* __restrict__ Ag) {
  // 12 foreign O-slices (32q x 33-padded d) + per-wave m/l. 51.7KB.
  __shared__ float Oex[12][32 * 33];
  __shared__ float Mdump[4][32], Ldump[4][32];

  const int tid = threadIdx.x;
  const int lane = tid & 63;
  const int wv = tid >> 6;  // K-split quarter
  const int l31 = lane & 31, hi = lane >> 5;

  // XCD-pinned decode: id%8 = (b,kv) group -> one XCD's L2 holds its K/V/Q.
  const int id = blockIdx.x;
  const int grp = id & 7;
  const int b = grp >> 2, kv = grp & 3;
  const int rest = id >> 3;          // 0..255 within group
  const int hh = rest & 3;           // head within kv group
  const int t = 63 - (rest >> 2);    // heavy strips first
  const int h = (kv << 2) | hh;
  const int bh = (b << 4) | h;
  const int rs = t * 32;  // strip q-row base

  const u16* Qb = Q + ((size_t)bh * 64 + t) * 4096;
  const u16* Kb = Kr + (size_t)(b * KV_ + kv) * 64 * 4096;
  const u16* Vb = Vt + (size_t)(b * KV_ + kv) * 64 * 4096;

  // Q as B-operand: lane holds Q[q=l31][w*16 + hi*8 .. +8] for w=0..7
  bf16x8 qf[8];
#pragma unroll
  for (int w = 0; w < 8; w++)
    qf[w] = *(const bf16x8*)(Qb + w * 512 + lane * 8);

  float m_s = -1e30f, l_s = 0.f;
  f32x16 oacc[4];
#pragma unroll
  for (int dt = 0; dt < 4; dt++)
#pragma unroll
    for (int i = 0; i < 16; i++) oacc[dt][i] = 0.f;

  // 4-way K-range split; wave3 owns the diagonal tile.
  const int klo = ((t + 1) * wv) >> 2;
  const int khi = ((t + 1) * (wv + 1)) >> 2;

  bf16x8 kf[8];  // single buffer, prefetch-after-use (WAR-safe)
  auto loadK = [&](int jt) {
    const u16* kp = Kb + (size_t)jt * 4096 + lane * 8;
#pragma unroll
    for (int w = 0; w < 8; w++) kf[w] = *(const bf16x8*)(kp + w * 512);
  };

  auto step = [&](int jt) {
    // V A-fragments for this tile (consumed after softmax) — issue first
    const u16* vp = Vb + (size_t)jt * 4096 + lane * 8;
    bf16x8 vf[8];  // [dt*2+kk]
#pragma unroll
    for (int f = 0; f < 8; f++)
      vf[f] = *(const bf16x8*)(vp + f * 512);

    // S^T = K·Q^T, two independent 4-deep chains over d
    f32x16 s0, s1;
#pragma unroll
    for (int i = 0; i < 16; i++) { s0[i] = 0.f; s1[i] = 0.f; }
    __builtin_amdgcn_s_setprio(1);
#pragma unroll
    for (int dc = 0; dc < 4; dc++) {
      s0 = __builtin_amdgcn_mfma_f32_32x32x16_bf16(kf[2 * dc], qf[2 * dc], s0,
                                                   0, 0, 0);
      s1 = __builtin_amdgcn_mfma_f32_32x32x16_bf16(kf[2 * dc + 1],
                                                   qf[2 * dc + 1], s1, 0, 0, 0);
    }
    __builtin_amdgcn_s_setprio(0);
    // prefetch next tile's K into the (now-read) buffer
    if (jt + 1 < khi) loadK(jt + 1);
    f32x16 s = s0 + s1;

    if (jt == t) {  // diagonal tile causal mask: k_local > q_local
#pragma unroll
      for (int r = 0; r < 16; r++) {
        const int kl = (r & 3) + 8 * (r >> 2) + 4 * hi;
        if (kl > l31) s[r] = -1e30f;
      }
    }
    // row max: in-lane tree + one cross-half shuffle
    float mx4[4];
#pragma unroll
    for (int g = 0; g < 4; g++)
      mx4[g] = fmaxf(fmaxf(s[4 * g], s[4 * g + 1]),
                     fmaxf(s[4 * g + 2], s[4 * g + 3]));
    float mx = fmaxf(fmaxf(mx4[0], mx4[1]), fmaxf(mx4[2], mx4[3]));
    mx = fmaxf(mx, __shfl_xor(mx, 32));
    // defer-max (THR=8): skip rescale while growth bounded
    const bool defer = __all(mx - m_s <= 8.f);
    const float mn = defer ? m_s : fmaxf(m_s, mx);
    if (!defer) {
      const float alpha = __expf(m_s - mn);
      m_s = mn;
      l_s *= alpha;
#pragma unroll
      for (int dt = 0; dt < 4; dt++)
#pragma unroll
        for (int i = 0; i < 16; i++) oacc[dt][i] *= alpha;
    }
    // exp + row sum
    float rs4[4];
#pragma unroll
    for (int g = 0; g < 4; g++) {
      float e0 = __expf(s[4 * g + 0] - mn);
      float e1 = __expf(s[4 * g + 1] - mn);
      float e2 = __expf(s[4 * g + 2] - mn);
      float e3 = __expf(s[4 * g + 3] - mn);
      s[4 * g + 0] = e0; s[4 * g + 1] = e1;
      s[4 * g + 2] = e2; s[4 * g + 3] = e3;
      rs4[g] = (e0 + e1) + (e2 + e3);
    }
    float rsum = (rs4[0] + rs4[1]) + (rs4[2] + rs4[3]);
    rsum += __shfl_xor(rsum, 32);
    l_s += rsum;
    // pack P to bf16 words and exchange across lane-halves to build B-frags:
    // kk=0 needs k=8*hi..8*hi+7; kk=1 needs k=16+8*hi..+7.
    unsigned a0 = pk2(s[0], s[1]),  b0 = pk2(s[2], s[3]);
    unsigned c0 = pk2(s[4], s[5]),  d0 = pk2(s[6], s[7]);
    unsigned e0 = pk2(s[8], s[9]),  f0 = pk2(s[10], s[11]);
    unsigned g0 = pk2(s[12], s[13]), h0w = pk2(s[14], s[15]);
    unsigned r1 = __shfl_xor(hi ? a0 : c0, 32);
    unsigned r2 = __shfl_xor(hi ? b0 : d0, 32);
    unsigned r3 = __shfl_xor(hi ? e0 : g0, 32);
    unsigned r4 = __shfl_xor(hi ? f0 : h0w, 32);
    union U16B { unsigned u[4]; bf16x8 v; };
    U16B p0, p1;
    p0.u[0] = hi ? r1 : a0;  p0.u[1] = hi ? r2 : b0;
    p0.u[2] = hi ? c0 : r1;  p0.u[3] = hi ? d0 : r2;
    p1.u[0] = hi ? r3 : e0;  p1.u[1] = hi ? r4 : f0;
    p1.u[2] = hi ? g0 : r3;  p1.u[3] = hi ? h0w : r4;
    // PV: O^T[d][q] accumulate, 4 independent d-tiles x 2 chained k-halves
    __builtin_amdgcn_s_setprio(1);
#pragma unroll
    for (int dt = 0; dt < 4; dt++) {
      oacc[dt] = __builtin_amdgcn_mfma_f32_32x32x16_bf16(vf[dt * 2], p0.v,
                                                         oacc[dt], 0, 0, 0);
      oacc[dt] = __builtin_amdgcn_mfma_f32_32x32x16_bf16(vf[dt * 2 + 1], p1.v,
                                                         oacc[dt], 0, 0, 0);
    }
    __builtin_amdgcn_s_setprio(0);
  };

  if (klo < khi) {
    loadK(klo);
    for (int jt = klo; jt < khi; jt++) step(jt);
  }

  // ---- 4-way flash merge. Stats + 3 foreign d-slices per wave to LDS.
  if (hi == 0) {
    Mdump[wv][l31] = m_s;
    Ldump[wv][l31] = l_s;
  }
  // slot(dt, src) = dt*3 + (src > dt ? src-1 : src); stride-33 rows (no bank
  // conflicts; 2-way hi-alias is free).
  auto dumpO = [&](auto wvc) {
    constexpr int WV = decltype(wvc)::value;
#pragma unroll
    for (int dt = 0; dt < 4; dt++) {
      if (dt == WV) continue;
      const int slot = dt * 3 + (WV > dt ? WV - 1 : WV);
      float* dst = &Oex[slot][l31 * 33];
#pragma unroll
      for (int g = 0; g < 4; g++)
#pragma unroll
        for (int j = 0; j < 4; j++)
          dst[8 * g + 4 * hi + j] = oacc[dt][4 * g + j];
    }
  };
  if (wv == 0) dumpO(ic<0>{});
  else if (wv == 1) dumpO(ic<1>{});
  else if (wv == 2) dumpO(ic<2>{});
  else dumpO(ic<3>{});
  __syncthreads();
  // Each wave finalizes its OWN d-slice: merge 4 partials + gate + frag store.
  auto finO = [&](auto wvc) {
    constexpr int WV = decltype(wvc)::value;
    const float m01 = fmaxf(Mdump[0][l31], Mdump[1][l31]);
    const float m23 = fmaxf(Mdump[2][l31], Mdump[3][l31]);
    const float mstar = fmaxf(m01, m23);
    float al[4];
    float L = 0.f;
#pragma unroll
    for (int u = 0; u < 4; u++) {
      al[u] = __expf(Mdump[u][l31] - mstar);
      L += Ldump[u][l31] * al[u];
    }
    const float linv = 1.f / L;
    float ov[16];
#pragma unroll
    for (int i2 = 0; i2 < 16; i2++) ov[i2] = oacc[WV][i2] * al[WV];
#pragma unroll
    for (int u = 0; u < 4; u++) {
      if (u == WV) continue;
      const int slot = WV * 3 + (u > WV ? u - 1 : u);
      const float* src = &Oex[slot][l31 * 33];
#pragma unroll
      for (int g = 0; g < 4; g++)
#pragma unroll
        for (int j = 0; j < 4; j++)
          ov[4 * g + j] += al[u] * src[8 * g + 4 * hi + j];
    }
    const size_t tok = (size_t)b * S_ + rs + l31;
    const u16* gp = qraw + tok * TS_ + h * 256 + 128;
#pragma unroll
    for (int g = 0; g < 4; g++) {
      const int dbase = WV * 32 + 8 * g + 4 * hi;
      const int dg = h * 128 + dbase;  // global col in Ag (K=2048)
      uint2 gv = *(const uint2*)(gp + dbase);
      float g0 = b2f((u16)(gv.x & 0xffff)), g1 = b2f((u16)(gv.x >> 16));
      float g2 = b2f((u16)(gv.y & 0xffff)), g3 = b2f((u16)(gv.y >> 16));
      float o0 = ov[4 * g + 0] * linv / (1.f + __expf(-g0));
      float o1 = ov[4 * g + 1] * linv / (1.f + __expf(-g1));
      float o2 = ov[4 * g + 2] * linv / (1.f + __expf(-g2));
      float o3 = ov[4 * g + 3] * linv / (1.f + __expf(-g3));
      const size_t off =
          (((tok >> 4) * 64 + (dg >> 5)) * 64 + ((dg >> 3) & 3) * 16 +
           (tok & 15)) * 8 + 4 * hi;
      *(uint2*)(Ag + off) = make_uint2(pk2(o0, o1), pk2(o2, o3));
    }
  };
  if (wv == 0) finO(ic<0>{});
  else if (wv == 1) finO(ic<1>{});
  else if (wv == 2) finO(ic<2>{});
  else finO(ic<3>{});
}

extern "C" void kernel_launch(void* const* d_in, const int* in_sizes, int n_in,
                              void* d_out, int out_size, void* d_ws,
                              size_t ws_size, hipStream_t stream) {
  const float* x  = (const float*)d_in[0];
  const float* Wq = (const float*)d_in[1];
  const float* Wk = (const float*)d_in[2];
  const float* Wv = (const float*)d_in[3];
  const float* Wo = (const float*)d_in[4];
  const float* qn = (const float*)d_in[5];
  const float* kn = (const float*)d_in[6];
  float* out = (float*)d_out;
  char* ws = (char*)d_ws;

  u16* xb    = (u16*)(ws + 0);          // 16.8 MB  x bf16 A-frag (4096x2048)
  u16* Wqt   = (u16*)(ws + 16777216);   // 16.8 MB  Wq^T B-frag (4096x2048)
  u16* Wkvt  = (u16*)(ws + 33554432);   //  4.2 MB  [Wk^T; Wv^T] B-frag (contig)
  u16* Wot   = (u16*)(ws + 37748736);   //  8.4 MB  Wo^T B-frag (2048x2048)
  u16* qkraw = (u16*)(ws + 46137344);   // 41.9 MB  [q|gate|k|v] row-major
  u16* Vtb   = (u16*)(ws + 88080384);   //  4.2 MB  V fragments (attn)
  u16* Kr    = (u16*)(ws + 92274688);   //  4.2 MB  K roped fragments (attn)
  u16* Ag    = (u16*)(ws + 96468992);   // 16.8 MB  gated attn A-frag (4096x2048)
  u16* Qr = xb;  // roped+scaled Q fragments (aliases xb, dead after QKV GEMM)

  // prep0: 4x W-transpose (14336 blocks) + cast (4096 blocks)
  prep0_kernel<<<18432, 256, 0, stream>>>(Wq, Wk, Wv, Wo, x, Wqt, Wkvt, Wot, xb);

  // merged QKV projection: Bt = [Wq^T; Wk^T; Wv^T] (5120 x 2048 frag, contig)
  gemm_nt<u16><<<1280, 256, 0, stream>>>(xb, Wqt, qkraw, 4096, TS_, 2048);

  // prep1: rmsrope Q (16384) + rmsrope K (4096) + transpose_v (2048)
  prep1_kernel<<<22528, 256, 0, stream>>>(qkraw, qn, kn, Qr, Kr, Vtb);

  attn_kernel<<<2048, 256, 0, stream>>>(Qr, Kr, Vtb, qkraw, Ag);
  gemm_nt<float><<<512, 256, 0, stream>>>(Ag, Wot, out, 4096, 2048, 2048);
}

// Round 11
// 363.273 us; speedup vs baseline: 1.3573x; 1.3573x over previous
//
#include <hip/hip_runtime.h>
#include <hip/hip_bf16.h>

typedef unsigned short u16;
typedef __bf16 bf16x8 __attribute__((ext_vector_type(8)));
typedef float f32x4 __attribute__((ext_vector_type(4)));
typedef float f32x16 __attribute__((ext_vector_type(16)));

#define B_   2
#define S_   2048
#define HID_ 2048
#define H_   16
#define KV_  4
#define D_   128
#define TS_  5120  // merged qkv token stride (4096 q|gate + 512 k + 512 v)

template <int V> struct ic { static constexpr int value = V; };

__device__ __forceinline__ u16 f2b(float f) {
  unsigned u = __float_as_uint(f);
  return (u16)((u + 0x7fffu + ((u >> 16) & 1u)) >> 16);  // RNE
}
__device__ __forceinline__ float b2f(u16 h) {
  return __uint_as_float(((unsigned)h) << 16);
}
__device__ __forceinline__ unsigned pk2(float a, float b) {
  __hip_bfloat162 h = __float22bfloat162_rn(make_float2(a, b));
  unsigned u;
  __builtin_memcpy(&u, &h, 4);
  return u;  // a low 16, b high 16
}
__device__ __forceinline__ void cstore(float* p, float v) { *p = v; }
__device__ __forceinline__ void cstore(u16* p, float v)   { *p = f2b(v); }

// async global->LDS, 16B per lane; LDS dest = wave-uniform base + lane*16
__device__ __forceinline__ void gl_lds16(const u16* g, u16* l) {
  __builtin_amdgcn_global_load_lds(
      (const __attribute__((address_space(1))) unsigned int*)g,
      (__attribute__((address_space(3))) unsigned int*)l, 16, 0, 0);
}

// GEMM-operand fragment layout for an (R x K) matrix, R%16==0, K%32==0:
//   addr(r,k) = (((r>>4)*(K>>5) + (k>>5))*64 + ((k>>3)&3)*16 + (r&15))*8 + (k&7)
// One (tile,kstep) block = 1KB, lane l = oct(l>>4)*16 + row(l&15) — exactly the
// mfma_16x16x32 A/B fragment. Staging reads are lane-contiguous 1KB; LDS reads
// linear; both conflict- and scatter-free.

// ---------------- prep0: {Wq,Wk,Wv,Wo transpose->B-frag} + {cast x->A-frag}
// fused into one range-decoded launch (was 5 launches -> 1).
__global__ __launch_bounds__(256)
void prep0_kernel(const float* __restrict__ Wq, const float* __restrict__ Wk,
                  const float* __restrict__ Wv, const float* __restrict__ Wo,
                  const float* __restrict__ x, u16* __restrict__ Wqt,
                  u16* __restrict__ Wkvt, u16* __restrict__ Wot,
                  u16* __restrict__ xb) {
  __shared__ u16 t[32][33];
  const int tid = threadIdx.x;
  int idx = blockIdx.x;
  if (idx >= 14336) {  // ---- cast x -> bf16 A-frag (4096 blocks)
    idx -= 14336;
    const int gi = idx * 256 + tid;
    const int r = gi >> 8;
    const int k = (gi & 255) << 3;
    const float4 v0 = *(const float4*)(x + (size_t)r * 2048 + k);
    const float4 v1 = *(const float4*)(x + (size_t)r * 2048 + k + 4);
    uint4 w;
    w.x = pk2(v0.x, v0.y); w.y = pk2(v0.z, v0.w);
    w.z = pk2(v1.x, v1.y); w.w = pk2(v1.z, v1.w);
    const size_t off =
        ((((size_t)(r >> 4) * 64 + (k >> 5)) * 64) + ((k >> 3) & 3) * 16 +
         (r & 15)) * 8;
    *(uint4*)(xb + off) = w;
    return;
  }
  // ---- W transpose -> B-frag layout
  const float* in; u16* out; int Cc, bx, by;
  if (idx < 8192)       { in = Wq; out = Wqt; Cc = 4096; bx = idx & 127; by = idx >> 7; }
  else if (idx < 9216)  { idx -= 8192; in = Wk; out = Wkvt; Cc = 512; bx = idx & 15; by = idx >> 4; }
  else if (idx < 10240) { idx -= 9216; in = Wv; out = Wkvt + (size_t)512 * 2048; Cc = 512; bx = idx & 15; by = idx >> 4; }
  else                  { idx -= 10240; in = Wo; out = Wot; Cc = 2048; bx = idx & 63; by = idx >> 6; }
  const int R = 2048;  // K-dim for all weight operands
  const int tx = tid & 31, ty = tid >> 5;
  const int c0 = bx * 32, r0 = by * 32;
#pragma unroll
  for (int i = 0; i < 4; i++)
    t[ty + i * 8][tx] = f2b(in[(size_t)(r0 + ty + i * 8) * Cc + c0 + tx]);
  __syncthreads();
  if (tid < 128) {
    const int tl = tid >> 6, l = tid & 63, li = l & 15, quad = l >> 4;
    u16 vals[8];
#pragma unroll
    for (int e = 0; e < 8; e++) vals[e] = t[quad * 8 + e][tl * 16 + li];
    const size_t off =
        ((((size_t)(c0 >> 4) + tl) * (R >> 5) + (r0 >> 5)) * 64 + quad * 16 +
         li) * 8;
    *(uint4*)(out + off) = *(const uint4*)vals;
  }
}

// ---------------- rmsrope body: fused RMSNorm (w+1) + RoPE, attn-frag output
__device__ __forceinline__ void rmsrope_body(
    int relblk, int tid, const u16* __restrict__ in,
    const float* __restrict__ w, u16* __restrict__ out, int n_heads,
    int head_stride, float scale) {
  const int warp = (relblk << 2) + (tid >> 6);
  const int lane = tid & 63;
  const int h = warp % n_heads;
  const int tok = warp / n_heads;
  const int s = tok & (S_ - 1);
  const int b = tok >> 11;
  const u16* src = in + (size_t)tok * TS_ + (size_t)h * head_stride;
  float x1 = b2f(src[lane]);
  float x2 = b2f(src[lane + 64]);
  float ss = x1 * x1 + x2 * x2;
#pragma unroll
  for (int off = 1; off < 64; off <<= 1) ss += __shfl_xor(ss, off);
  const float inv = rsqrtf(ss * (1.0f / 128.0f) + 1e-6f) * scale;
  x1 *= inv * (w[lane] + 1.0f);
  x2 *= inv * (w[lane + 64] + 1.0f);
  const float invf = exp2f((float)lane * (-19.931568569324174f / 64.0f));
  const float ang = (float)s * invf;
  float sn, c;
  sincosf(ang, &sn, &c);
  const int wq = lane >> 4, hi = (lane >> 3) & 1, e = lane & 7;
  const size_t tb = (((size_t)b * n_heads + h) * 64 + (s >> 5)) * 4096;
  const size_t o1 = tb + (size_t)(wq * 64 + hi * 32 + (s & 31)) * 8 + e;
  out[o1]        = f2b(x1 * c - x2 * sn);
  out[o1 + 2048] = f2b(x2 * c + x1 * sn);
}

// ---------------- prep1: {rmsrope Q, rmsrope K, transpose_v} fused (3 -> 1)
__global__ __launch_bounds__(256)
void prep1_kernel(const u16* __restrict__ qkraw, const float* __restrict__ qn,
                  const float* __restrict__ kn, u16* __restrict__ Qr,
                  u16* __restrict__ Kr, u16* __restrict__ Vtb) {
  const int tid = threadIdx.x;
  int blk = blockIdx.x;
  if (blk < 16384) {  // Q: 65536 head-tokens, scale folded in
    rmsrope_body(blk, tid, qkraw, qn, Qr, 16, 256, 0.08838834764831845f);
    return;
  }
  blk -= 16384;
  if (blk < 4096) {  // K
    rmsrope_body(blk, tid, qkraw + 4096, kn, Kr, 4, 128, 1.0f);
    return;
  }
  blk -= 4096;  // transpose_v: idx in [0,2048)
  __shared__ u16 t[32][33];
  const int tx = tid & 31, ty = tid >> 5;
  const int jt = blk & 63, dt = (blk >> 6) & 3, z = blk >> 8;
  const int s0 = jt * 32, d0 = dt * 32;
  const int b = z >> 2, kv = z & 3;
  const u16* in = qkraw + 4096 + 512;
#pragma unroll
  for (int i = 0; i < 4; i++)
    t[ty + i * 8][tx] =
        in[(size_t)(b * S_ + s0 + ty + i * 8) * TS_ + kv * D_ + d0 + tx];
  __syncthreads();
  if (tid < 128) {
    const int kk = tid >> 6, hi2 = (tid >> 5) & 1, d31 = tid & 31;
    u16 vals[8];
#pragma unroll
    for (int e = 0; e < 8; e++) vals[e] = t[kk * 16 + hi2 * 8 + e][d31];
    const size_t off =
        ((((size_t)(b * KV_ + kv) * 64 + jt) * 8 + dt * 2 + kk) * 64 +
         hi2 * 32 + d31) * 8;
    *(uint4*)(Vtb + off) = *(const uint4*)vals;
  }
}

// --------------------------------- NT GEMM: A, Bt in FRAGMENT layout; C (M,N)
// row-major. 128x128 tile, BK=32, gl_lds16 width=16, single-barrier LDS
// double-buffer, zero bank conflicts. XCD-pinned 1D grid, n-fastest within
// group. Requires Nd%1024==0, Md=4096.
template <typename CT>
__global__ __launch_bounds__(256)
void gemm_nt(const u16* __restrict__ A, const u16* __restrict__ Bt,
             CT* __restrict__ C, int Md, int Nd, int Kd) {
  __shared__ u16 As[2][8 * 512];  // dbuf x 8 frag-tiles x 512 (16KB)
  __shared__ u16 Bs[2][8 * 512];
  const int tid = threadIdx.x;
  const int lane = tid & 63;
  const int wave = tid >> 6;
  const int wm = wave >> 1, wn = wave & 1;
  const int li = lane & 15, quad = lane >> 4;

  // XCD-pinned decode, n-fastest within group
  const int id = blockIdx.x;
  const int grp = id & 7;
  const int r = id >> 3;
  const int px = Nd >> 10;  // N-panels per XCD (5120->5, 2048->2)
  const int m0 = (r / px) * 128;
  const int n0 = (grp * px + (r % px)) * 128;

  f32x4 acc[4][4];
#pragma unroll
  for (int i = 0; i < 4; i++)
#pragma unroll
    for (int j = 0; j < 4; j++) acc[i][j] = (f32x4){0.f, 0.f, 0.f, 0.f};

  const size_t ts = (size_t)(Kd >> 5) * 512;  // elems per frag-tile row
  const u16* Ab = A + ((size_t)(m0 >> 4) + wave * 2) * ts + lane * 8;
  const u16* Bb = Bt + ((size_t)(n0 >> 4) + wave * 2) * ts + lane * 8;

  auto stage = [&](int buf, int k0) {
    const size_t ko = (size_t)k0 * 16;  // (k0>>5)*512
    gl_lds16(Ab + ko, &As[buf][(wave * 2) * 512]);
    gl_lds16(Ab + ts + ko, &As[buf][(wave * 2 + 1) * 512]);
    gl_lds16(Bb + ko, &Bs[buf][(wave * 2) * 512]);
    gl_lds16(Bb + ts + ko, &Bs[buf][(wave * 2 + 1) * 512]);
  };

  stage(0, 0);
  int cur = 0;
  for (int k0 = 0; k0 < Kd; k0 += 32) {
    __syncthreads();  // drains the stage of buf[cur] (issued last iter/prologue)
    if (k0 + 32 < Kd) stage(cur ^ 1, k0 + 32);
    bf16x8 af[4], bfr[4];
#pragma unroll
    for (int mt = 0; mt < 4; mt++)
      af[mt] = *(const bf16x8*)&As[cur][(wm * 4 + mt) * 512 + lane * 8];
#pragma unroll
    for (int nt = 0; nt < 4; nt++)
      bfr[nt] = *(const bf16x8*)&Bs[cur][(wn * 4 + nt) * 512 + lane * 8];
#pragma unroll
    for (int mt = 0; mt < 4; mt++)
#pragma unroll
      for (int nt = 0; nt < 4; nt++)
        acc[mt][nt] = __builtin_amdgcn_mfma_f32_16x16x32_bf16(
            af[mt], bfr[nt], acc[mt][nt], 0, 0, 0);
    cur ^= 1;
  }
#pragma unroll
  for (int mt = 0; mt < 4; mt++) {
    const int row = m0 + wm * 64 + mt * 16 + quad * 4;
#pragma unroll
    for (int nt = 0; nt < 4; nt++) {
      const int col = n0 + wn * 64 + nt * 16 + li;
#pragma unroll
      for (int r2 = 0; r2 < 4; r2++)
        cstore(&C[(size_t)(row + r2) * Nd + col], acc[mt][nt][r2]);
    }
  }
}

// --------------------------- flash attention: 2-wave split-K per 32-row strip,
// 32x32x16 MFMA, swapped QK^T, in-register P exchange, defer-max THR=8,
// XCD-pinned grid decode, heavy-strips-first, T5 setprio around MFMA clusters.
// Q/K/V pre-fragmented (1KB wave reads). Epilogue writes Ag in GEMM A-frag
// layout. All oacc[] indices compile-time (rule #20). REVERTED from the 4-way
// split (R10): its launch_bounds VGPR cap (170 < ~230 live) spilled the loop
// state to scratch (WRITE_SIZE 18MB->342MB) and its 51.7KB LDS capped
// residency at 3 blocks/CU vs this version's all-resident 8 blocks/CU.
// New: gate loads hoisted above the merge barrier (latency hidden under dump).
__global__ __launch_bounds__(128, 2)
void attn_kernel(const u16* __restrict__ Q, const u16* __restrict__ Kr,
                 const u16* __restrict__ Vt, const u16* __restrict__ qraw,
                 u16* __restrict__ Ag) {
  // epilogue-only LDS: per-wave f32 O-exchange [32][68] + m/l dumps. 17.9KB.
  __shared__ __align__(16) float Wscr[2][2176];
  __shared__ float Mdump[2][32], Ldump[2][32];

  const int tid = threadIdx.x;
  const int lane = tid & 63;
  const int wv = tid >> 6;  // K-split half (0 = low tiles, 1 = high tiles)
  const int l31 = lane & 31, hi = lane >> 5;

  // XCD-pinned decode: id%8 = (b,kv) group -> one XCD's L2 holds its K/V/Q.
  const int id = blockIdx.x;
  const int grp = id & 7;
  const int b = grp >> 2, kv = grp & 3;
  const int rest = id >> 3;          // 0..255 within group
  const int hh = rest & 3;           // head within kv group
  const int t = 63 - (rest >> 2);    // heavy strips first
  const int h = (kv << 2) | hh;
  const int bh = (b << 4) | h;
  const int rs = t * 32;  // strip q-row base

  const u16* Qb = Q + ((size_t)bh * 64 + t) * 4096;
  const u16* Kb = Kr + (size_t)(b * KV_ + kv) * 64 * 4096;
  const u16* Vb = Vt + (size_t)(b * KV_ + kv) * 64 * 4096;

  // Q as B-operand: lane holds Q[q=l31][w*16 + hi*8 .. +8] for w=0..7
  bf16x8 qf[8];
#pragma unroll
  for (int w = 0; w < 8; w++)
    qf[w] = *(const bf16x8*)(Qb + w * 512 + lane * 8);

  float m_s = -1e30f, l_s = 0.f;
  f32x16 oacc[4];
#pragma unroll
  for (int dt = 0; dt < 4; dt++)
#pragma unroll
    for (int i = 0; i < 16; i++) oacc[dt][i] = 0.f;

  // K-range split: wave0 [0,h0), wave1 [h0, t]; wave1 owns the diagonal.
  const int h0 = (t + 2) >> 1;
  const int klo = wv ? h0 : 0;
  const int khi = wv ? (t + 1) : h0;

  bf16x8 kf[8];  // single buffer, prefetch-after-use (WAR-safe)
  auto loadK = [&](int jt) {
    const u16* kp = Kb + (size_t)jt * 4096 + lane * 8;
#pragma unroll
    for (int w = 0; w < 8; w++) kf[w] = *(const bf16x8*)(kp + w * 512);
  };

  auto step = [&](int jt) {
    // V A-fragments for this tile (consumed after softmax) — issue first
    const u16* vp = Vb + (size_t)jt * 4096 + lane * 8;
    bf16x8 vf[8];  // [dt*2+kk]
#pragma unroll
    for (int f = 0; f < 8; f++)
      vf[f] = *(const bf16x8*)(vp + f * 512);

    // S^T = K·Q^T, two independent 4-deep chains over d
    f32x16 s0, s1;
#pragma unroll
    for (int i = 0; i < 16; i++) { s0[i] = 0.f; s1[i] = 0.f; }
    __builtin_amdgcn_s_setprio(1);
#pragma unroll
    for (int dc = 0; dc < 4; dc++) {
      s0 = __builtin_amdgcn_mfma_f32_32x32x16_bf16(kf[2 * dc], qf[2 * dc], s0,
                                                   0, 0, 0);
      s1 = __builtin_amdgcn_mfma_f32_32x32x16_bf16(kf[2 * dc + 1],
                                                   qf[2 * dc + 1], s1, 0, 0, 0);
    }
    __builtin_amdgcn_s_setprio(0);
    // prefetch next tile's K into the (now-read) buffer
    if (jt + 1 < khi) loadK(jt + 1);
    f32x16 s = s0 + s1;

    if (jt == t) {  // diagonal tile causal mask: k_local > q_local
#pragma unroll
      for (int r = 0; r < 16; r++) {
        const int kl = (r & 3) + 8 * (r >> 2) + 4 * hi;
        if (kl > l31) s[r] = -1e30f;
      }
    }
    // row max: in-lane tree + one cross-half shuffle
    float mx4[4];
#pragma unroll
    for (int g = 0; g < 4; g++)
      mx4[g] = fmaxf(fmaxf(s[4 * g], s[4 * g + 1]),
                     fmaxf(s[4 * g + 2], s[4 * g + 3]));
    float mx = fmaxf(fmaxf(mx4[0], mx4[1]), fmaxf(mx4[2], mx4[3]));
    mx = fmaxf(mx, __shfl_xor(mx, 32));
    // defer-max (THR=8): skip rescale while growth bounded
    const bool defer = __all(mx - m_s <= 8.f);
    const float mn = defer ? m_s : fmaxf(m_s, mx);
    if (!defer) {
      const float alpha = __expf(m_s - mn);
      m_s = mn;
      l_s *= alpha;
#pragma unroll
      for (int dt = 0; dt < 4; dt++)
#pragma unroll
        for (int i = 0; i < 16; i++) oacc[dt][i] *= alpha;
    }
    // exp + row sum
    float rs4[4];
#pragma unroll
    for (int g = 0; g < 4; g++) {
      float e0 = __expf(s[4 * g + 0] - mn);
      float e1 = __expf(s[4 * g + 1] - mn);
      float e2 = __expf(s[4 * g + 2] - mn);
      float e3 = __expf(s[4 * g + 3] - mn);
      s[4 * g + 0] = e0; s[4 * g + 1] = e1;
      s[4 * g + 2] = e2; s[4 * g + 3] = e3;
      rs4[g] = (e0 + e1) + (e2 + e3);
    }
    float rsum = (rs4[0] + rs4[1]) + (rs4[2] + rs4[3]);
    rsum += __shfl_xor(rsum, 32);
    l_s += rsum;
    // pack P to bf16 words and exchange across lane-halves to build B-frags:
    // kk=0 needs k=8*hi..8*hi+7; kk=1 needs k=16+8*hi..+7.
    unsigned a0 = pk2(s[0], s[1]),  b0 = pk2(s[2], s[3]);
    unsigned c0 = pk2(s[4], s[5]),  d0 = pk2(s[6], s[7]);
    unsigned e0 = pk2(s[8], s[9]),  f0 = pk2(s[10], s[11]);
    unsigned g0 = pk2(s[12], s[13]), h0w = pk2(s[14], s[15]);
    unsigned r1 = __shfl_xor(hi ? a0 : c0, 32);
    unsigned r2 = __shfl_xor(hi ? b0 : d0, 32);
    unsigned r3 = __shfl_xor(hi ? e0 : g0, 32);
    unsigned r4 = __shfl_xor(hi ? f0 : h0w, 32);
    union U16B { unsigned u[4]; bf16x8 v; };
    U16B p0, p1;
    p0.u[0] = hi ? r1 : a0;  p0.u[1] = hi ? r2 : b0;
    p0.u[2] = hi ? c0 : r1;  p0.u[3] = hi ? d0 : r2;
    p1.u[0] = hi ? r3 : e0;  p1.u[1] = hi ? r4 : f0;
    p1.u[2] = hi ? g0 : r3;  p1.u[3] = hi ? h0w : r4;
    // PV: O^T[d][q] accumulate, 4 independent d-tiles x 2 chained k-halves
    __builtin_amdgcn_s_setprio(1);
#pragma unroll
    for (int dt = 0; dt < 4; dt++) {
      oacc[dt] = __builtin_amdgcn_mfma_f32_32x32x16_bf16(vf[dt * 2], p0.v,
                                                         oacc[dt], 0, 0, 0);
      oacc[dt] = __builtin_amdgcn_mfma_f32_32x32x16_bf16(vf[dt * 2 + 1], p1.v,
                                                         oacc[dt], 0, 0, 0);
    }
    __builtin_amdgcn_s_setprio(0);
  };

  if (klo < khi) {
    loadK(klo);
    for (int jt = klo; jt < khi; jt++) step(jt);
  }

  // ---- gate pre-load (independent of merge): hide HBM/L2 latency under the
  // O-dump + barrier. Indices compile-time via WV template (rule #20).
  const size_t tok = (size_t)b * S_ + rs + l31;
  const u16* gp = qraw + tok * TS_ + h * 256 + 128;
  uint2 gvh[2][4];
  auto preG = [&](auto wvc) {
    constexpr int WV = decltype(wvc)::value;
#pragma unroll
    for (int i = 0; i < 2; i++)
#pragma unroll
      for (int g = 0; g < 4; g++)
        gvh[i][g] =
            *(const uint2*)(gp + (WV * 2 + i) * 32 + 8 * g + 4 * hi);
  };
  if (wv == 0) preG(ic<0>{}); else preG(ic<1>{});

  // ---- cross-wave flash merge. Phase 1: dump COMPLEMENTARY half (dts) + m,l.
  float* myscr = &Wscr[wv][0];
  auto dumpO = [&](auto wvc) {
    constexpr int WV = decltype(wvc)::value;
#pragma unroll
    for (int i = 0; i < 2; i++) {
#pragma unroll
      for (int g = 0; g < 4; g++) {
        f32x4 w;
        w[0] = oacc[(1 - WV) * 2 + i][4 * g + 0];
        w[1] = oacc[(1 - WV) * 2 + i][4 * g + 1];
        w[2] = oacc[(1 - WV) * 2 + i][4 * g + 2];
        w[3] = oacc[(1 - WV) * 2 + i][4 * g + 3];
        *(f32x4*)&myscr[l31 * 68 + i * 32 + 8 * g + 4 * hi] = w;
      }
    }
    if (hi == 0) {
      Mdump[WV][l31] = m_s;
      Ldump[WV][l31] = l_s;
    }
  };
  if (wv == 0) dumpO(ic<0>{}); else dumpO(ic<1>{});
  __syncthreads();
  // Phase 2: finalize OWN half (merge + gate + store in GEMM A-frag layout).
  auto finO = [&](auto wvc) {
    constexpr int WV = decltype(wvc)::value;
    const float* oscr = &Wscr[1 - WV][0];
    const float mo = Mdump[1 - WV][l31];
    const float lo2 = Ldump[1 - WV][l31];
    const float mm = fmaxf(m_s, mo);
    const float as = __expf(m_s - mm), ao = __expf(mo - mm);
    const float linv = 1.f / (l_s * as + lo2 * ao);
#pragma unroll
    for (int i = 0; i < 2; i++) {
#pragma unroll
      for (int g = 0; g < 4; g++) {
        const int dbase = (WV * 2 + i) * 32 + 8 * g + 4 * hi;
        const int dg = h * 128 + dbase;  // global col in Ag (K=2048)
        f32x4 oo = *(const f32x4*)&oscr[l31 * 68 + i * 32 + 8 * g + 4 * hi];
        const uint2 gv = gvh[i][g];
        float g0 = b2f((u16)(gv.x & 0xffff)), g1 = b2f((u16)(gv.x >> 16));
        float g2 = b2f((u16)(gv.y & 0xffff)), g3 = b2f((u16)(gv.y >> 16));
        float o0 = (oacc[WV * 2 + i][4 * g + 0] * as + oo[0] * ao) * linv /
                   (1.f + __expf(-g0));
        float o1 = (oacc[WV * 2 + i][4 * g + 1] * as + oo[1] * ao) * linv /
                   (1.f + __expf(-g1));
        float o2 = (oacc[WV * 2 + i][4 * g + 2] * as + oo[2] * ao) * linv /
                   (1.f + __expf(-g2));
        float o3 = (oacc[WV * 2 + i][4 * g + 3] * as + oo[3] * ao) * linv /
                   (1.f + __expf(-g3));
        const size_t off =
            (((tok >> 4) * 64 + (dg >> 5)) * 64 + ((dg >> 3) & 3) * 16 +
             (tok & 15)) * 8 + 4 * hi;
        *(uint2*)(Ag + off) = make_uint2(pk2(o0, o1), pk2(o2, o3));
      }
    }
  };
  if (wv == 0) finO(ic<0>{}); else finO(ic<1>{});
}

extern "C" void kernel_launch(void* const* d_in, const int* in_sizes, int n_in,
                              void* d_out, int out_size, void* d_ws,
                              size_t ws_size, hipStream_t stream) {
  const float* x  = (const float*)d_in[0];
  const float* Wq = (const float*)d_in[1];
  const float* Wk = (const float*)d_in[2];
  const float* Wv = (const float*)d_in[3];
  const float* Wo = (const float*)d_in[4];
  const float* qn = (const float*)d_in[5];
  const float* kn = (const float*)d_in[6];
  float* out = (float*)d_out;
  char* ws = (char*)d_ws;

  u16* xb    = (u16*)(ws + 0);          // 16.8 MB  x bf16 A-frag (4096x2048)
  u16* Wqt   = (u16*)(ws + 16777216);   // 16.8 MB  Wq^T B-frag (4096x2048)
  u16* Wkvt  = (u16*)(ws + 33554432);   //  4.2 MB  [Wk^T; Wv^T] B-frag (contig)
  u16* Wot   = (u16*)(ws + 37748736);   //  8.4 MB  Wo^T B-frag (2048x2048)
  u16* qkraw = (u16*)(ws + 46137344);   // 41.9 MB  [q|gate|k|v] row-major
  u16* Vtb   = (u16*)(ws + 88080384);   //  4.2 MB  V fragments (attn)
  u16* Kr    = (u16*)(ws + 92274688);   //  4.2 MB  K roped fragments (attn)
  u16* Ag    = (u16*)(ws + 96468992);   // 16.8 MB  gated attn A-frag (4096x2048)
  u16* Qr = xb;  // roped+scaled Q fragments (aliases xb, dead after QKV GEMM)

  // prep0: 4x W-transpose (14336 blocks) + cast (4096 blocks)
  prep0_kernel<<<18432, 256, 0, stream>>>(Wq, Wk, Wv, Wo, x, Wqt, Wkvt, Wot, xb);

  // merged QKV projection: Bt = [Wq^T; Wk^T; Wv^T] (5120 x 2048 frag, contig)
  gemm_nt<u16><<<1280, 256, 0, stream>>>(xb, Wqt, qkraw, 4096, TS_, 2048);

  // prep1: rmsrope Q (16384) + rmsrope K (4096) + transpose_v (2048)
  prep1_kernel<<<22528, 256, 0, stream>>>(qkraw, qn, kn, Qr, Kr, Vtb);

  attn_kernel<<<2048, 128, 0, stream>>>(Qr, Kr, Vtb, qkraw, Ag);
  gemm_nt<float><<<512, 256, 0, stream>>>(Ag, Wot, out, 4096, 2048, 2048);
}